// Round 9
// baseline (801.776 us; speedup 1.0000x reference)
//
#include <hip/hip_runtime.h>

#define Bdim 64
#define Ndim 512
#define Hdim 2048
#define NCHUNK 8
#define LNEPS 1e-5f
#define WMAT_ELEMS (Hdim * Hdim)
#define OTILE 32
#define KC 128

typedef unsigned short u16;
typedef __attribute__((ext_vector_type(8))) short short8;
typedef __attribute__((ext_vector_type(4))) float f32x4;

__device__ __forceinline__ u16 f2bf(float f) {
    unsigned int u = __float_as_uint(f);
    return (u16)((u + 0x7FFFu + ((u >> 16) & 1u)) >> 16);
}
__device__ __forceinline__ float bf2f(u16 s) {
    return __uint_as_float(((unsigned int)s) << 16);
}

// One-time prep: 7 bf16 weight views in [o][k] layout + clip in bf16.
__global__ __launch_bounds__(256)
void convert_w(const float* __restrict__ Wc, const float* __restrict__ Wt,
               const float* __restrict__ Wl, const float* __restrict__ Wg,
               const float* __restrict__ Wo, const float* __restrict__ Wp,
               const float* __restrict__ clip,
               u16* __restrict__ dst, u16* __restrict__ clip16)
{
    __shared__ float L[64][65];
    const int t   = threadIdx.x;
    const int bid = blockIdx.x;
    if (bid < 5120) {
        const int mid = bid >> 10;
        const int tb  = bid & 1023;
        const float* src = (mid == 0) ? Wc : (mid == 1) ? Wt : (mid == 2) ? Wl
                         : (mid == 3) ? Wg : Wo;
        u16* out = dst + (size_t)mid * WMAT_ELEMS;
        const size_t base = (size_t)tb * 4096 + (size_t)t * 16;
#pragma unroll
        for (int i = 0; i < 2; ++i) {
            float4 a = *(const float4*)(src + base + i * 8);
            float4 b = *(const float4*)(src + base + i * 8 + 4);
            short8 s;
            s[0] = (short)f2bf(a.x); s[1] = (short)f2bf(a.y);
            s[2] = (short)f2bf(a.z); s[3] = (short)f2bf(a.w);
            s[4] = (short)f2bf(b.x); s[5] = (short)f2bf(b.y);
            s[6] = (short)f2bf(b.z); s[7] = (short)f2bf(b.w);
            *(short8*)(out + base + i * 8) = s;
        }
    } else if (bid < 7168) {
        const int mid = 5 + ((bid - 5120) >> 10);
        const int tb  = (bid - 5120) & 1023;
        const float* src = (mid == 5) ? Wp : Wl;
        u16* out = dst + (size_t)mid * WMAT_ELEMS;
        const int k0 = (tb & 31) * 64;
        const int o0 = (tb >> 5) * 64;
        const int row = t >> 2;
        const int cq  = t & 3;
#pragma unroll
        for (int i = 0; i < 4; ++i) {
            float4 v = *(const float4*)(src + (size_t)(k0 + row) * Hdim + o0 + cq * 16 + i * 4);
            *(float4*)(&L[row][cq * 16 + i * 4]) = v;
        }
        __syncthreads();
        const int orow = t >> 2;
#pragma unroll
        for (int half = 0; half < 2; ++half) {
            short8 s;
#pragma unroll
            for (int i = 0; i < 8; ++i)
                s[i] = (short)f2bf(L[cq * 16 + half * 8 + i][orow]);
            *(short8*)(out + (size_t)(o0 + orow) * Hdim + k0 + cq * 16 + half * 8) = s;
        }
    } else {
        const int tb = bid - 7168;   // 0..31
        const size_t base = (size_t)tb * 4096 + (size_t)t * 16;
#pragma unroll
        for (int i = 0; i < 2; ++i) {
            float4 a = *(const float4*)(clip + base + i * 8);
            float4 b = *(const float4*)(clip + base + i * 8 + 4);
            short8 s;
            s[0] = (short)f2bf(a.x); s[1] = (short)f2bf(a.y);
            s[2] = (short)f2bf(a.z); s[3] = (short)f2bf(a.w);
            s[4] = (short)f2bf(b.x); s[5] = (short)f2bf(b.y);
            s[6] = (short)f2bf(b.z); s[7] = (short)f2bf(b.w);
            *(short8*)(clip16 + base + i * 8) = s;
        }
    }
}

// Full-K MFMA GEMV, direct output (no split-K, no combine):
// Y[b,o] = sum_k X16[b,k]*Wb[o][k] (+bias[o]) (+Y_old); writes f32 Y and bf16
// mirror Y16; FINAL also writes out (+loss slot).
// Grid 64 blocks = 32-col o-tiles; block 256 thr = 4 waves, each 16 rows.
// Double-buffered LDS, ONE barrier per K-iter. ~60 VGPR, no spill modes.
template<int HASBIAS, int ACC, int FINAL>
__global__ __launch_bounds__(256)
void mfma_gemv(const u16* __restrict__ X16, const u16* __restrict__ Wb,
               const float* __restrict__ bias,
               float* __restrict__ Y, u16* __restrict__ Y16,
               float* __restrict__ out, int has_loss)
{
    __shared__ short Xs[2][64][136];   // 64x128 bf16 + pad (stride 272B: 2-way max)
    __shared__ short Ws[2][OTILE][136];
    const int t  = threadIdx.x;
    const int o0 = blockIdx.x * OTILE;
    const int wv = t >> 6;
    const int ln = t & 63;
    const int xr = t & 63;            // X stage: row
    const int xg = t >> 6;            // X stage: 32-k group
    const int wn = t >> 3;            // W stage: o-row 0..31
    const int wk = (t & 7) * 16;      // W stage: 16-k group

    f32x4 acc[2];
#pragma unroll
    for (int i = 0; i < 2; ++i)
#pragma unroll
        for (int j = 0; j < 4; ++j) acc[i][j] = 0.f;

    uint4 qx[4], qw[2];
    auto gload = [&](int k0) {
#pragma unroll
        for (int i = 0; i < 4; ++i)
            qx[i] = *(const uint4*)(X16 + (size_t)xr * Hdim + k0 + xg * 32 + i * 8);
        qw[0] = *(const uint4*)(Wb + (size_t)(o0 + wn) * Hdim + k0 + wk);
        qw[1] = *(const uint4*)(Wb + (size_t)(o0 + wn) * Hdim + k0 + wk + 8);
    };
    auto lstore = [&](int buf) {
#pragma unroll
        for (int i = 0; i < 4; ++i)
            *(uint4*)(&Xs[buf][xr][xg * 32 + i * 8]) = qx[i];
        *(uint4*)(&Ws[buf][wn][wk])     = qw[0];
        *(uint4*)(&Ws[buf][wn][wk + 8]) = qw[1];
    };

    gload(0);
    lstore(0);
    __syncthreads();
    for (int c = 0; c < 16; ++c) {
        const int cur = c & 1;
        if (c < 15) gload((c + 1) * KC);
#pragma unroll
        for (int kstep = 0; kstep < 4; ++kstep) {
            const int kf = kstep * 32 + (ln >> 4) * 8;
            short8 af = *(const short8*)(&Xs[cur][16 * wv + (ln & 15)][kf]);
#pragma unroll
            for (int n4 = 0; n4 < 2; ++n4) {
                short8 bf = *(const short8*)(&Ws[cur][n4 * 16 + (ln & 15)][kf]);
                acc[n4] = __builtin_amdgcn_mfma_f32_16x16x32_bf16(af, bf, acc[n4], 0, 0, 0);
            }
        }
        if (c < 15) lstore(cur ^ 1);
        __syncthreads();
    }
#pragma unroll
    for (int n4 = 0; n4 < 2; ++n4) {
        const int col = o0 + n4 * 16 + (ln & 15);
        float bv = 0.f;
        if (HASBIAS) bv = bias[col];
#pragma unroll
        for (int r = 0; r < 4; ++r) {
            const int row = 16 * wv + (ln >> 4) * 4 + r;
            float v = acc[n4][r] + bv;
            if (ACC) v += Y[(size_t)row * Hdim + col];
            Y[(size_t)row * Hdim + col] = v;
            Y16[(size_t)row * Hdim + col] = f2bf(v);
            if (FINAL) out[(size_t)row * Hdim + col] = v;
        }
    }
    if (FINAL && has_loss && t == 0 && blockIdx.x == 0) out[Bdim * Hdim] = 0.f;
}

// One (b, 8-row n-chunk): scores -> local softmax -> partial weighted sum.
// FIRST: read f32 lfb + write bf16 cache; else read bf16 cache (L3-resident).
template<int FIRST>
__global__ __launch_bounds__(256, 4)
void flash_chunk(const float* __restrict__ lfb, const u16* __restrict__ lfb16r,
                 u16* __restrict__ lfb16w, const float* __restrict__ thetal,
                 float scale, u16* __restrict__ up,
                 float* __restrict__ wm, float* __restrict__ wz)
{
    __shared__ u16 T[NCHUNK][Hdim];   // 32 KB
    __shared__ float th[Hdim];        // 8 KB
    __shared__ float sc[NCHUNK];
    __shared__ float wts[NCHUNK];
    const int t  = threadIdx.x;
    const int b  = blockIdx.x >> 6;
    const int ch = blockIdx.x & 63;
    const size_t nbase = (size_t)b * Ndim + ch * NCHUNK;
#pragma unroll
    for (int i = 0; i < 16; ++i) {
        int flat4 = i * 256 + t;
        int row   = flat4 >> 9;
        int c4    = flat4 & 511;
        if (FIRST) {
            float4 v = *(const float4*)(lfb + (nbase + row) * Hdim + c4 * 4);
            ushort4 u4;
            u4.x = f2bf(v.x); u4.y = f2bf(v.y); u4.z = f2bf(v.z); u4.w = f2bf(v.w);
            *(ushort4*)(&T[row][c4 * 4]) = u4;
            *(ushort4*)(lfb16w + (nbase + row) * Hdim + c4 * 4) = u4;
        } else {
            ushort4 u4 = *(const ushort4*)(lfb16r + (nbase + row) * Hdim + c4 * 4);
            *(ushort4*)(&T[row][c4 * 4]) = u4;
        }
    }
#pragma unroll
    for (int i = 0; i < 2; ++i) {
        int c = (i * 256 + t) * 4;
        float4 v = *(const float4*)(thetal + (size_t)b * Hdim + c);
        *(float4*)(&th[c]) = v;
    }
    __syncthreads();
    const int wv = t >> 6, ln = t & 63;
#pragma unroll
    for (int q = 0; q < 2; ++q) {
        int n = wv * 2 + q;
        float a = 0.f;
#pragma unroll
        for (int i = 0; i < 8; ++i) {
            int c = ln * 4 + i * 256;
            ushort4 x = *(const ushort4*)(&T[n][c]);
            float4 y  = *(const float4*)(&th[c]);
            a += bf2f(x.x) * y.x + bf2f(x.y) * y.y + bf2f(x.z) * y.z + bf2f(x.w) * y.w;
        }
#pragma unroll
        for (int off = 32; off; off >>= 1) a += __shfl_xor(a, off, 64);
        if (ln == 0) sc[n] = a * scale;
    }
    __syncthreads();
    float m = sc[0];
#pragma unroll
    for (int n = 1; n < NCHUNK; ++n) m = fmaxf(m, sc[n]);
    if (t < NCHUNK) wts[t] = expf(sc[t] - m);
    __syncthreads();
    if (t == 0) {
        float z = 0.f;
#pragma unroll
        for (int n = 0; n < NCHUNK; ++n) z += wts[n];
        wm[blockIdx.x] = m;
        wz[blockIdx.x] = z;
    }
#pragma unroll
    for (int i = 0; i < 8; ++i) {
        int c = t + i * 256;
        float a = 0.f;
#pragma unroll
        for (int n = 0; n < NCHUNK; ++n) a += wts[n] * bf2f(T[n][c]);
        up[(size_t)blockIdx.x * Hdim + c] = f2bf(a);
    }
}

// Merge 64 chunk-softmaxes per b; write u directly as bf16 (gemv consumes bf16).
__global__ __launch_bounds__(256)
void flash_comb(const u16* __restrict__ up, const float* __restrict__ wm,
                const float* __restrict__ wz, u16* __restrict__ u16out)
{
    __shared__ float mm[64], zz[64], ee[64];
    const int t  = threadIdx.x;
    const int b  = blockIdx.x >> 3;
    const int sl = blockIdx.x & 7;
    if (t < 64) { mm[t] = wm[b * 64 + t]; zz[t] = wz[b * 64 + t]; }
    __syncthreads();
    float mg = mm[0];
#pragma unroll
    for (int i = 1; i < 64; ++i) mg = fmaxf(mg, mm[i]);
    if (t < 64) ee[t] = expf(mm[t] - mg);
    __syncthreads();
    float Z = 0.f;
#pragma unroll
    for (int i = 0; i < 64; ++i) Z += zz[i] * ee[i];
    const float inv = 1.f / Z;
    const int col = sl * 256 + t;
    float a = 0.f;
#pragma unroll 8
    for (int ch = 0; ch < 64; ++ch)
        a += ee[ch] * bf2f(up[(size_t)(b * 64 + ch) * Hdim + col]);
    u16out[(size_t)b * Hdim + col] = f2bf(a * inv);
}

// r16 = bf16(relu(layernorm(t))), t = f32 [64][2048] (bias already added)
__global__ __launch_bounds__(256)
void ln_relu(const float* __restrict__ tin, u16* __restrict__ r16)
{
    __shared__ float red[8];
    const int t = threadIdx.x, b = blockIdx.x;
    float4 v0 = *(const float4*)(tin + (size_t)b * Hdim + t * 4);
    float4 v1 = *(const float4*)(tin + (size_t)b * Hdim + (256 + t) * 4);
    float sum = v0.x + v0.y + v0.z + v0.w + v1.x + v1.y + v1.z + v1.w;
    float sq  = v0.x*v0.x + v0.y*v0.y + v0.z*v0.z + v0.w*v0.w
              + v1.x*v1.x + v1.y*v1.y + v1.z*v1.z + v1.w*v1.w;
#pragma unroll
    for (int off = 32; off; off >>= 1) {
        sum += __shfl_xor(sum, off, 64);
        sq  += __shfl_xor(sq,  off, 64);
    }
    if ((t & 63) == 0) { red[t >> 6] = sum; red[4 + (t >> 6)] = sq; }
    __syncthreads();
    sum = red[0] + red[1] + red[2] + red[3];
    sq  = red[4] + red[5] + red[6] + red[7];
    const float mu   = sum * (1.f / Hdim);
    const float var  = sq * (1.f / Hdim) - mu * mu;
    const float rstd = rsqrtf(var + LNEPS);
    ushort4 o0, o1;
    o0.x = f2bf(fmaxf(0.f, (v0.x - mu) * rstd));
    o0.y = f2bf(fmaxf(0.f, (v0.y - mu) * rstd));
    o0.z = f2bf(fmaxf(0.f, (v0.z - mu) * rstd));
    o0.w = f2bf(fmaxf(0.f, (v0.w - mu) * rstd));
    o1.x = f2bf(fmaxf(0.f, (v1.x - mu) * rstd));
    o1.y = f2bf(fmaxf(0.f, (v1.y - mu) * rstd));
    o1.z = f2bf(fmaxf(0.f, (v1.z - mu) * rstd));
    o1.w = f2bf(fmaxf(0.f, (v1.w - mu) * rstd));
    *(ushort4*)(r16 + (size_t)b * Hdim + t * 4)         = o0;
    *(ushort4*)(r16 + (size_t)b * Hdim + (256 + t) * 4) = o1;
}

extern "C" void kernel_launch(void* const* d_in, const int* in_sizes, int n_in,
                              void* d_out, int out_size, void* d_ws, size_t ws_size,
                              hipStream_t stream) {
    (void)in_sizes; (void)n_in; (void)ws_size;
    const float* clip = (const float*)d_in[0];
    const float* lfb  = (const float*)d_in[1];
    const float* Wc   = (const float*)d_in[2];
    const float* bc   = (const float*)d_in[3];
    const float* Wl   = (const float*)d_in[4];
    const float* bl   = (const float*)d_in[5];
    const float* Wt   = (const float*)d_in[6];
    const float* bt   = (const float*)d_in[7];
    const float* Wp   = (const float*)d_in[8];
    // d_in[9] = bp: cancels in softmax (per-row constant) -> unused
    const float* Wg   = (const float*)d_in[10];
    const float* bg   = (const float*)d_in[11];
    const float* Wo   = (const float*)d_in[12];
    const float* bo   = (const float*)d_in[13];
    float* out = (float*)d_out;

    // Workspace (f32 slots); u16 buffers counted in f32 slots.
    float* wsf    = (float*)d_ws;
    float* A      = wsf;                      // 131072
    float* thetal = wsf + 131072;             // 131072
    float* tY     = wsf + 262144;             // 131072
    float* scrY   = wsf + 393216;             // 131072 (dead f32 outs)
    u16*   A16    = (u16*)(wsf + 524288);     // 65536 slots each
    u16*   th16   = (u16*)(wsf + 589824);
    u16*   tp16   = (u16*)(wsf + 655360);
    u16*   s16    = (u16*)(wsf + 720896);
    u16*   ubuf   = (u16*)(wsf + 786432);
    u16*   r16    = (u16*)(wsf + 851968);
    u16*   clip16 = (u16*)(wsf + 917504);
    u16*   junk16 = (u16*)(wsf + 983040);     // dead bf16 mirrors
    float* wm     = wsf + 1048576;            // 4096
    float* wz     = wsf + 1052672;            // 4096
    u16*   up     = (u16*)(wsf + 1056768);    // 4194304 slots -> 5251072
    u16*   lfb16  = (u16*)(wsf + 5251072);    // 33554432 slots -> 38805504
    u16*   Wbf    = (u16*)(wsf + 38805504);   // 7*2097152 slots (~214 MB total)

    u16* bWc  = Wbf + (size_t)0 * WMAT_ELEMS;
    u16* bWt  = Wbf + (size_t)1 * WMAT_ELEMS;
    u16* bWl  = Wbf + (size_t)2 * WMAT_ELEMS;
    u16* bWg  = Wbf + (size_t)3 * WMAT_ELEMS;
    u16* bWo  = Wbf + (size_t)4 * WMAT_ELEMS;
    u16* bWpT = Wbf + (size_t)5 * WMAT_ELEMS;
    u16* bWlT = Wbf + (size_t)6 * WMAT_ELEMS;

    const float scale = 0.022097086912079608f;   // 1/sqrt(2048)
    dim3 blk(256);
    const int has_loss = (out_size > Bdim * Hdim) ? 1 : 0;

    convert_w<<<7200, blk, 0, stream>>>(Wc, Wt, Wl, Wg, Wo, Wp, clip, Wbf, clip16);

    // A = clip @ Wc^T + bc
    mfma_gemv<1,0,0><<<64, blk, 0, stream>>>(clip16, bWc, bc, A, A16, nullptr, 0);

    for (int l = 0; l < 3; ++l) {
        // theta = A @ Wt^T + bt
        mfma_gemv<1,0,0><<<64, blk, 0, stream>>>(A16, bWt, bt, scrY, th16, nullptr, 0);
        // thetap = theta @ Wp
        mfma_gemv<0,0,0><<<64, blk, 0, stream>>>(th16, bWpT, nullptr, scrY, tp16, nullptr, 0);
        // thetal = thetap @ Wl
        mfma_gemv<0,0,0><<<64, blk, 0, stream>>>(tp16, bWlT, nullptr, thetal, junk16, nullptr, 0);
        // fused scores/softmax/weighted-sum over lfb
        if (l == 0)
            flash_chunk<1><<<4096, blk, 0, stream>>>(lfb, nullptr, lfb16, thetal, scale, up, wm, wz);
        else
            flash_chunk<0><<<4096, blk, 0, stream>>>(nullptr, lfb16, nullptr, thetal, scale, up, wm, wz);
        flash_comb<<<512, blk, 0, stream>>>(up, wm, wz, ubuf);
        // s = u @ Wl^T + bl
        mfma_gemv<1,0,0><<<64, blk, 0, stream>>>(ubuf, bWl, bl, scrY, s16, nullptr, 0);
        // t = s @ Wg^T + bg
        mfma_gemv<1,0,0><<<64, blk, 0, stream>>>(s16, bWg, bg, tY, junk16, nullptr, 0);
        // r = relu(LN(t))
        ln_relu<<<64, blk, 0, stream>>>(tY, r16);
        // A += r @ Wo^T + bo   (last layer also writes out + loss)
        if (l < 2)
            mfma_gemv<1,1,0><<<64, blk, 0, stream>>>(r16, bWo, bo, A, A16, nullptr, 0);
        else
            mfma_gemv<1,1,1><<<64, blk, 0, stream>>>(r16, bWo, bo, A, A16, out, has_loss);
    }
}

// Round 10
// 427.123 us; speedup vs baseline: 1.8772x; 1.8772x over previous
//
#include <hip/hip_runtime.h>

#define Bdim 64
#define Ndim 512
#define Hdim 2048
#define KSPLIT 8
#define NCHUNK 8
#define LNEPS 1e-5f
#define WMAT_ELEMS (Hdim * Hdim)

typedef unsigned short u16;
typedef __attribute__((ext_vector_type(8))) short short8;
typedef __attribute__((ext_vector_type(4))) float f32x4;

__device__ __forceinline__ u16 f2bf(float f) {
    unsigned int u = __float_as_uint(f);
    return (u16)((u + 0x7FFFu + ((u >> 16) & 1u)) >> 16);
}
__device__ __forceinline__ float bf2f(u16 s) {
    return __uint_as_float(((unsigned int)s) << 16);
}

// One-time prep: 6 bf16 weight views in [o][k] layout.
// bid<4096: direct convert Wt,Wl,Wg,Wo  (mid 0..3)
// else    : transpose-convert Wp,Wl -> bWpT(4), bWlT(5)
__global__ __launch_bounds__(256)
void convert_w(const float* __restrict__ Wt, const float* __restrict__ Wl,
               const float* __restrict__ Wg, const float* __restrict__ Wo,
               const float* __restrict__ Wp, u16* __restrict__ dst)
{
    __shared__ float L[64][65];
    const int t   = threadIdx.x;
    const int bid = blockIdx.x;
    if (bid < 4096) {
        const int mid = bid >> 10;
        const int tb  = bid & 1023;
        const float* src = (mid == 0) ? Wt : (mid == 1) ? Wl : (mid == 2) ? Wg : Wo;
        u16* out = dst + (size_t)mid * WMAT_ELEMS;
        const size_t base = (size_t)tb * 4096 + (size_t)t * 16;
#pragma unroll
        for (int i = 0; i < 2; ++i) {
            float4 a = *(const float4*)(src + base + i * 8);
            float4 b = *(const float4*)(src + base + i * 8 + 4);
            short8 s;
            s[0] = (short)f2bf(a.x); s[1] = (short)f2bf(a.y);
            s[2] = (short)f2bf(a.z); s[3] = (short)f2bf(a.w);
            s[4] = (short)f2bf(b.x); s[5] = (short)f2bf(b.y);
            s[6] = (short)f2bf(b.z); s[7] = (short)f2bf(b.w);
            *(short8*)(out + base + i * 8) = s;
        }
    } else {
        const int mid = 4 + ((bid - 4096) >> 10);
        const int tb  = (bid - 4096) & 1023;
        const float* src = (mid == 4) ? Wp : Wl;
        u16* out = dst + (size_t)mid * WMAT_ELEMS;
        const int k0 = (tb & 31) * 64;
        const int o0 = (tb >> 5) * 64;
        const int row = t >> 2;
        const int cq  = t & 3;
#pragma unroll
        for (int i = 0; i < 4; ++i) {
            float4 v = *(const float4*)(src + (size_t)(k0 + row) * Hdim + o0 + cq * 16 + i * 4);
            *(float4*)(&L[row][cq * 16 + i * 4]) = v;
        }
        __syncthreads();
        const int orow = t >> 2;
#pragma unroll
        for (int half = 0; half < 2; ++half) {
            short8 s;
#pragma unroll
            for (int i = 0; i < 8; ++i)
                s[i] = (short)f2bf(L[cq * 16 + half * 8 + i][orow]);
            *(short8*)(out + (size_t)(o0 + orow) * Hdim + k0 + cq * 16 + half * 8) = s;
        }
    }
}

// MFMA GEMV (R7-proven): part[ks][b][o] = sum_{k in ks-range} X[b,k]*W[o][k]
// XF32/WF32: stage from f32 with inline bf16 convert (single-use inputs).
// Grid 256 = 8 ks x 32 o-tiles(64). 4 waves. No launch_bounds cap (R5 lesson),
// no consumer-side partial sums (R4/R8 lesson), no fences (R3 lesson).
template<int XF32, int WF32>
__global__ __launch_bounds__(256)
void mfma_gemv(const u16* __restrict__ X16, const float* __restrict__ Xf,
               const u16* __restrict__ Wb, const float* __restrict__ Wf,
               float* __restrict__ part)
{
    __shared__ short Xs[64][72];   // row stride 144B -> conflict-benign
    __shared__ short Ws[64][72];
    const int t  = threadIdx.x;
    const int nt = blockIdx.x & 31;
    const int ks = blockIdx.x >> 5;
    const int o0 = nt * 64;
    const int kb = ks * 256;
    const int wv = t >> 6;
    const int ln = t & 63;
    const int xr = t & 63;            // X stage: row
    const int xg = t >> 6;            // X stage: 16-k group
    const int wn = t >> 2;            // W stage: o-row
    const int wk = (t & 3) * 16;      // W stage: 16-k group

    f32x4 acc[4];
#pragma unroll
    for (int i = 0; i < 4; ++i)
#pragma unroll
        for (int j = 0; j < 4; ++j) acc[i][j] = 0.f;

    uint4  qx[2];
    float4 px[4];
    uint4  qw[2];
    float4 pw[4];
    auto gload = [&](int k0) {
        if (!XF32) {
            qx[0] = *(const uint4*)(X16 + (size_t)xr * Hdim + k0 + xg * 16);
            qx[1] = *(const uint4*)(X16 + (size_t)xr * Hdim + k0 + xg * 16 + 8);
        } else {
#pragma unroll
            for (int i = 0; i < 4; ++i)
                px[i] = *(const float4*)(Xf + (size_t)xr * Hdim + k0 + xg * 16 + i * 4);
        }
        if (!WF32) {
            qw[0] = *(const uint4*)(Wb + (size_t)(o0 + wn) * Hdim + k0 + wk);
            qw[1] = *(const uint4*)(Wb + (size_t)(o0 + wn) * Hdim + k0 + wk + 8);
        } else {
#pragma unroll
            for (int i = 0; i < 4; ++i)
                pw[i] = *(const float4*)(Wf + (size_t)(o0 + wn) * Hdim + k0 + wk + i * 4);
        }
    };
    auto cvt8 = [](const float4& a, const float4& b) {
        short8 s;
        s[0] = (short)f2bf(a.x); s[1] = (short)f2bf(a.y);
        s[2] = (short)f2bf(a.z); s[3] = (short)f2bf(a.w);
        s[4] = (short)f2bf(b.x); s[5] = (short)f2bf(b.y);
        s[6] = (short)f2bf(b.z); s[7] = (short)f2bf(b.w);
        return s;
    };
    auto lstore = [&]() {
        if (!XF32) {
            *(uint4*)(&Xs[xr][xg * 16])     = qx[0];
            *(uint4*)(&Xs[xr][xg * 16 + 8]) = qx[1];
        } else {
            *(short8*)(&Xs[xr][xg * 16])     = cvt8(px[0], px[1]);
            *(short8*)(&Xs[xr][xg * 16 + 8]) = cvt8(px[2], px[3]);
        }
        if (!WF32) {
            *(uint4*)(&Ws[wn][wk])     = qw[0];
            *(uint4*)(&Ws[wn][wk + 8]) = qw[1];
        } else {
            *(short8*)(&Ws[wn][wk])     = cvt8(pw[0], pw[1]);
            *(short8*)(&Ws[wn][wk + 8]) = cvt8(pw[2], pw[3]);
        }
    };

    gload(kb);
    for (int c = 0; c < 4; ++c) {
        __syncthreads();
        lstore();
        __syncthreads();
        if (c < 3) gload(kb + (c + 1) * 64);
#pragma unroll
        for (int kstep = 0; kstep < 2; ++kstep) {
            const int kf = kstep * 32 + (ln >> 4) * 8;
            short8 af = *(const short8*)(&Xs[16 * wv + (ln & 15)][kf]);
#pragma unroll
            for (int n4 = 0; n4 < 4; ++n4) {
                short8 bf = *(const short8*)(&Ws[n4 * 16 + (ln & 15)][kf]);
                acc[n4] = __builtin_amdgcn_mfma_f32_16x16x32_bf16(af, bf, acc[n4], 0, 0, 0);
            }
        }
    }
#pragma unroll
    for (int n4 = 0; n4 < 4; ++n4) {
#pragma unroll
        for (int r = 0; r < 4; ++r) {
            const int brow = 16 * wv + (ln >> 4) * 4 + r;
            part[(size_t)(ks * 64 + brow) * Hdim + o0 + n4 * 16 + (ln & 15)] = acc[n4][r];
        }
    }
}

// Y[b,o] (=|+=) sum_s part[s][b][o] (+bias); writes f32 Y + bf16 mirror Y16;
// FINAL also writes out (+ loss slot).
template<int HASBIAS, int ACC, int FINAL>
__global__ __launch_bounds__(256)
void combine(const float* __restrict__ part, const float* __restrict__ bias,
             float* __restrict__ Y, u16* __restrict__ Y16,
             float* __restrict__ out, int has_loss)
{
    const int flat4 = blockIdx.x * 256 + threadIdx.x;   // 0..32767
    const size_t e  = (size_t)flat4 * 4;
    const int o     = (int)(e & (Hdim - 1));
    float4 v;
    if (HASBIAS) v = *(const float4*)(bias + o);
    else         v = make_float4(0.f, 0.f, 0.f, 0.f);
#pragma unroll
    for (int s = 0; s < KSPLIT; ++s) {
        float4 p = *(const float4*)(part + (size_t)s * (64 * Hdim) + e);
        v.x += p.x; v.y += p.y; v.z += p.z; v.w += p.w;
    }
    if (ACC) {
        float4 a = *(const float4*)(Y + e);
        v.x += a.x; v.y += a.y; v.z += a.z; v.w += a.w;
    }
    *(float4*)(Y + e) = v;
    ushort4 m;
    m.x = f2bf(v.x); m.y = f2bf(v.y); m.z = f2bf(v.z); m.w = f2bf(v.w);
    *(ushort4*)(Y16 + e) = m;
    if (FINAL) {
        *(float4*)(out + e) = v;
        if (has_loss && flat4 == 0) out[Bdim * Hdim] = 0.f;
    }
}

// One (b, 8-row n-chunk): theta_l summed from partials (64 KB L2-hot per
// block — NOT the XPART pattern), scores -> local softmax -> partial weighted
// sum (bf16). FIRST: read f32 lfb + write bf16 cache.
template<int FIRST>
__global__ __launch_bounds__(256, 4)
void flash_chunk(const float* __restrict__ lfb, const u16* __restrict__ lfb16r,
                 u16* __restrict__ lfb16w, const float* __restrict__ thpart,
                 float scale, u16* __restrict__ up,
                 float* __restrict__ wm, float* __restrict__ wz)
{
    __shared__ u16 T[NCHUNK][Hdim];   // 32 KB
    __shared__ float th[Hdim];        // 8 KB
    __shared__ float sc[NCHUNK];
    __shared__ float wts[NCHUNK];
    const int t  = threadIdx.x;
    const int b  = blockIdx.x >> 6;
    const int ch = blockIdx.x & 63;
    const size_t nbase = (size_t)b * Ndim + ch * NCHUNK;
#pragma unroll
    for (int i = 0; i < 16; ++i) {
        int flat4 = i * 256 + t;
        int row   = flat4 >> 9;
        int c4    = flat4 & 511;
        if (FIRST) {
            float4 v = *(const float4*)(lfb + (nbase + row) * Hdim + c4 * 4);
            ushort4 u4;
            u4.x = f2bf(v.x); u4.y = f2bf(v.y); u4.z = f2bf(v.z); u4.w = f2bf(v.w);
            *(ushort4*)(&T[row][c4 * 4]) = u4;
            *(ushort4*)(lfb16w + (nbase + row) * Hdim + c4 * 4) = u4;
        } else {
            ushort4 u4 = *(const ushort4*)(lfb16r + (nbase + row) * Hdim + c4 * 4);
            *(ushort4*)(&T[row][c4 * 4]) = u4;
        }
    }
#pragma unroll
    for (int i = 0; i < 2; ++i) {
        int c = (i * 256 + t) * 4;
        float4 v = make_float4(0.f, 0.f, 0.f, 0.f);
#pragma unroll
        for (int s = 0; s < KSPLIT; ++s) {
            float4 p = *(const float4*)(thpart + (size_t)(s * 64 + b) * Hdim + c);
            v.x += p.x; v.y += p.y; v.z += p.z; v.w += p.w;
        }
        *(float4*)(&th[c]) = v;
    }
    __syncthreads();
    const int wv = t >> 6, ln = t & 63;
#pragma unroll
    for (int q = 0; q < 2; ++q) {
        int n = wv * 2 + q;
        float a = 0.f;
#pragma unroll
        for (int i = 0; i < 8; ++i) {
            int c = ln * 4 + i * 256;
            ushort4 x = *(const ushort4*)(&T[n][c]);
            float4 y  = *(const float4*)(&th[c]);
            a += bf2f(x.x) * y.x + bf2f(x.y) * y.y + bf2f(x.z) * y.z + bf2f(x.w) * y.w;
        }
#pragma unroll
        for (int off = 32; off; off >>= 1) a += __shfl_xor(a, off, 64);
        if (ln == 0) sc[n] = a * scale;
    }
    __syncthreads();
    float m = sc[0];
#pragma unroll
    for (int n = 1; n < NCHUNK; ++n) m = fmaxf(m, sc[n]);
    if (t < NCHUNK) wts[t] = expf(sc[t] - m);
    __syncthreads();
    if (t == 0) {
        float z = 0.f;
#pragma unroll
        for (int n = 0; n < NCHUNK; ++n) z += wts[n];
        wm[blockIdx.x] = m;
        wz[blockIdx.x] = z;
    }
#pragma unroll
    for (int i = 0; i < 8; ++i) {
        int c = t + i * 256;
        float a = 0.f;
#pragma unroll
        for (int n = 0; n < NCHUNK; ++n) a += wts[n] * bf2f(T[n][c]);
        up[(size_t)blockIdx.x * Hdim + c] = f2bf(a);
    }
}

// Merge 64 chunk-softmaxes per b; u written as bf16 (only gemv reads it).
__global__ __launch_bounds__(256)
void flash_comb(const u16* __restrict__ up, const float* __restrict__ wm,
                const float* __restrict__ wz, u16* __restrict__ u16out)
{
    __shared__ float mm[64], zz[64], ee[64];
    const int t  = threadIdx.x;
    const int b  = blockIdx.x >> 3;
    const int sl = blockIdx.x & 7;
    if (t < 64) { mm[t] = wm[b * 64 + t]; zz[t] = wz[b * 64 + t]; }
    __syncthreads();
    float mg = mm[0];
#pragma unroll
    for (int i = 1; i < 64; ++i) mg = fmaxf(mg, mm[i]);
    if (t < 64) ee[t] = expf(mm[t] - mg);
    __syncthreads();
    float Z = 0.f;
#pragma unroll
    for (int i = 0; i < 64; ++i) Z += zz[i] * ee[i];
    const float inv = 1.f / Z;
    const int col = sl * 256 + t;
    float a = 0.f;
#pragma unroll 8
    for (int ch = 0; ch < 64; ++ch)
        a += ee[ch] * bf2f(up[(size_t)(b * 64 + ch) * Hdim + col]);
    u16out[(size_t)b * Hdim + col] = f2bf(a * inv);
}

// r16 = bf16(relu(layernorm(sum_s part[s][b][:] + bias)))
__global__ __launch_bounds__(256)
void ln_relu_part(const float* __restrict__ part, const float* __restrict__ bias,
                  u16* __restrict__ r16)
{
    __shared__ float trow[Hdim];
    __shared__ float red[8];
    const int t = threadIdx.x, b = blockIdx.x;
    float sum = 0.f, sq = 0.f;
#pragma unroll
    for (int i = 0; i < 2; ++i) {
        int c = (i * 256 + t) * 4;
        float4 v = *(const float4*)(bias + c);
#pragma unroll
        for (int s = 0; s < KSPLIT; ++s) {
            float4 p = *(const float4*)(part + ((size_t)(s * 64 + b)) * Hdim + c);
            v.x += p.x; v.y += p.y; v.z += p.z; v.w += p.w;
        }
        *(float4*)(&trow[c]) = v;
        sum += v.x + v.y + v.z + v.w;
        sq  += v.x * v.x + v.y * v.y + v.z * v.z + v.w * v.w;
    }
#pragma unroll
    for (int off = 32; off; off >>= 1) {
        sum += __shfl_xor(sum, off, 64);
        sq  += __shfl_xor(sq,  off, 64);
    }
    if ((t & 63) == 0) { red[t >> 6] = sum; red[4 + (t >> 6)] = sq; }
    __syncthreads();
    sum = red[0] + red[1] + red[2] + red[3];
    sq  = red[4] + red[5] + red[6] + red[7];
    const float mu   = sum * (1.f / Hdim);
    const float var  = sq * (1.f / Hdim) - mu * mu;
    const float rstd = rsqrtf(var + LNEPS);
#pragma unroll
    for (int i = 0; i < 2; ++i) {
        int c = (i * 256 + t) * 4;
        float4 v = *(const float4*)(&trow[c]);
        ushort4 o;
        o.x = f2bf(fmaxf(0.f, (v.x - mu) * rstd));
        o.y = f2bf(fmaxf(0.f, (v.y - mu) * rstd));
        o.z = f2bf(fmaxf(0.f, (v.z - mu) * rstd));
        o.w = f2bf(fmaxf(0.f, (v.w - mu) * rstd));
        *(ushort4*)(r16 + (size_t)b * Hdim + c) = o;
    }
}

extern "C" void kernel_launch(void* const* d_in, const int* in_sizes, int n_in,
                              void* d_out, int out_size, void* d_ws, size_t ws_size,
                              hipStream_t stream) {
    (void)in_sizes; (void)n_in; (void)ws_size;
    const float* clip = (const float*)d_in[0];
    const float* lfb  = (const float*)d_in[1];
    const float* Wc   = (const float*)d_in[2];
    const float* bc   = (const float*)d_in[3];
    const float* Wl   = (const float*)d_in[4];
    const float* bl   = (const float*)d_in[5];
    const float* Wt   = (const float*)d_in[6];
    const float* bt   = (const float*)d_in[7];
    const float* Wp   = (const float*)d_in[8];
    // d_in[9] = bp: cancels in softmax (per-row constant) -> unused
    const float* Wg   = (const float*)d_in[10];
    const float* bg   = (const float*)d_in[11];
    const float* Wo   = (const float*)d_in[12];
    const float* bo   = (const float*)d_in[13];
    float* out = (float*)d_out;

    // Workspace (f32 slots); u16 buffers counted in f32 slots.
    float* wsf    = (float*)d_ws;
    float* A      = wsf;                      // 131072
    float* scrY   = wsf + 131072;             // 131072 (dead f32 copies)
    u16*   A16    = (u16*)(wsf + 262144);     // 65536 slots each
    u16*   th16   = (u16*)(wsf + 327680);
    u16*   tp16   = (u16*)(wsf + 393216);
    u16*   s16    = (u16*)(wsf + 458752);
    u16*   ubuf   = (u16*)(wsf + 524288);
    u16*   r16    = (u16*)(wsf + 589824);
    float* wm     = wsf + 655360;             // 4096
    float* wz     = wsf + 659456;             // 4096
    float* PA     = wsf + 663552;             // 8*64*2048 = 1048576 -> 1712128
    u16*   up     = (u16*)(wsf + 1712128);    // 4194304 slots -> 5906432
    u16*   lfb16  = (u16*)(wsf + 5906432);    // 33554432 slots -> 39460864
    u16*   Wbf    = (u16*)(wsf + 39460864);   // 6*2097152 slots (~208 MB total)

    u16* bWt  = Wbf + (size_t)0 * WMAT_ELEMS;
    u16* bWl  = Wbf + (size_t)1 * WMAT_ELEMS;
    u16* bWg  = Wbf + (size_t)2 * WMAT_ELEMS;
    u16* bWo  = Wbf + (size_t)3 * WMAT_ELEMS;
    u16* bWpT = Wbf + (size_t)4 * WMAT_ELEMS;
    u16* bWlT = Wbf + (size_t)5 * WMAT_ELEMS;

    const float scale = 0.022097086912079608f;   // 1/sqrt(2048)
    dim3 blk(256);
    const int has_loss = (out_size > Bdim * Hdim) ? 1 : 0;

    // one-time: 6 bf16 weight views (Wc/clip converted inline below)
    convert_w<<<6144, blk, 0, stream>>>(Wt, Wl, Wg, Wo, Wp, Wbf);

    // A = clip @ Wc^T + bc   (f32 inputs, inline-converted during staging)
    mfma_gemv<1,1><<<256, blk, 0, stream>>>(nullptr, clip, nullptr, Wc, PA);
    combine<1,0,0><<<128, blk, 0, stream>>>(PA, bc, A, A16, nullptr, 0);

    for (int l = 0; l < 3; ++l) {
        // theta = A @ Wt^T + bt
        mfma_gemv<0,0><<<256, blk, 0, stream>>>(A16, nullptr, bWt, nullptr, PA);
        combine<1,0,0><<<128, blk, 0, stream>>>(PA, bt, scrY, th16, nullptr, 0);
        // thetap = theta @ Wp
        mfma_gemv<0,0><<<256, blk, 0, stream>>>(th16, nullptr, bWpT, nullptr, PA);
        combine<0,0,0><<<128, blk, 0, stream>>>(PA, nullptr, scrY, tp16, nullptr, 0);
        // thetal partials = thetap @ Wl   (flash sums them)
        mfma_gemv<0,0><<<256, blk, 0, stream>>>(tp16, nullptr, bWlT, nullptr, PA);
        // fused scores/softmax/weighted-sum over lfb
        if (l == 0)
            flash_chunk<1><<<4096, blk, 0, stream>>>(lfb, nullptr, lfb16, PA, scale, up, wm, wz);
        else
            flash_chunk<0><<<4096, blk, 0, stream>>>(nullptr, lfb16, nullptr, PA, scale, up, wm, wz);
        flash_comb<<<512, blk, 0, stream>>>(up, wm, wz, ubuf);
        // s = u @ Wl^T + bl
        mfma_gemv<0,0><<<256, blk, 0, stream>>>(ubuf, nullptr, bWl, nullptr, PA);
        combine<1,0,0><<<128, blk, 0, stream>>>(PA, bl, scrY, s16, nullptr, 0);
        // t partials = s @ Wg^T; r = relu(LN(sum + bg))
        mfma_gemv<0,0><<<256, blk, 0, stream>>>(s16, nullptr, bWg, nullptr, PA);
        ln_relu_part<<<64, blk, 0, stream>>>(PA, bg, r16);
        // A += r @ Wo^T + bo   (last layer also writes out + loss)
        mfma_gemv<0,0><<<256, blk, 0, stream>>>(r16, nullptr, bWo, nullptr, PA);
        if (l < 2)
            combine<1,1,0><<<128, blk, 0, stream>>>(PA, bo, A, A16, nullptr, 0);
        else
            combine<1,1,1><<<128, blk, 0, stream>>>(PA, bo, A, A16, out, has_loss);
    }
}